// Round 2
// baseline (104.810 us; speedup 1.0000x reference)
//
#include <hip/hip_runtime.h>

#define NB 4
#define NN 512
#define NF 64
#define NEG_SLOPE 0.2f
#define LN_EPS 1e-5f
#define JC 64

__device__ __forceinline__ float wave_sum(float v){
  #pragma unroll
  for (int d = 32; d; d >>= 1) v += __shfl_xor(v, d, 64);
  return v;
}
__device__ __forceinline__ float wave_max(float v){
  #pragma unroll
  for (int d = 32; d; d >>= 1) v = fmaxf(v, __shfl_xor(v, d, 64));
  return v;
}

// ws layout (floats):
//   r   [NN]              adj row-sums
//   evh [NB*NN*NF*2]      interleaved {exp(-Vh), h} per (b,n,f)
//   eU  [NB*NN*NF]        exp(-Uh)
//   li  [NB*NN]           h . a_i
//   lj  [NB*NN]           h . a_j
// total = 512 + 262144 + 131072 + 2048 + 2048 = 397824 floats (~1.52 MiB)

extern "C" __global__ __launch_bounds__(64)
void k_setup(const float* __restrict__ x, const float* __restrict__ adj,
             const float* __restrict__ Ww, const float* __restrict__ Wb,
             const float* __restrict__ Uw, const float* __restrict__ Ub,
             const float* __restrict__ Vw, const float* __restrict__ Vb,
             const float* __restrict__ attw,
             float* __restrict__ ws)
{
  float* r   = ws;
  float* evh = ws + NN;
  float* eU  = evh + NB*NN*NF*2;
  float* li  = eU + NB*NN*NF;
  float* lj  = li + NB*NN;

  const int blk  = blockIdx.x;
  const int lane = threadIdx.x;

  if (blk >= NB*NN) {               // adj row-sum blocks
    int j = blk - NB*NN;
    const float2* a2 = (const float2*)(adj + j*NN);
    float s = 0.f;
    #pragma unroll
    for (int t = 0; t < 4; t++){
      float2 a = a2[lane + 64*t];
      s += a.x + a.y;
    }
    s = wave_sum(s);
    if (lane == 0) r[j] = s;
    return;
  }

  const int row = blk;              // b*NN + n
  __shared__ float sx[NF];
  __shared__ float sh[NF];

  sx[lane] = x[row*NF + lane];
  __syncthreads();

  // h = x @ Ww^T + Wb  (lane = output feature)
  float hv = Wb[lane];
  {
    const float4* w4 = (const float4*)(Ww + lane*NF);
    #pragma unroll
    for (int t = 0; t < 16; t++){
      float4 w = w4[t];
      hv = fmaf(sx[4*t+0], w.x, hv);
      hv = fmaf(sx[4*t+1], w.y, hv);
      hv = fmaf(sx[4*t+2], w.z, hv);
      hv = fmaf(sx[4*t+3], w.w, hv);
    }
  }
  sh[lane] = hv;
  __syncthreads();

  float uh = Ub[lane];
  float vh = Vb[lane];
  {
    const float4* u4 = (const float4*)(Uw + lane*NF);
    const float4* v4 = (const float4*)(Vw + lane*NF);
    #pragma unroll
    for (int t = 0; t < 16; t++){
      float4 uu = u4[t]; float4 vv = v4[t];
      float h0 = sh[4*t+0], h1 = sh[4*t+1], h2 = sh[4*t+2], h3 = sh[4*t+3];
      uh = fmaf(h0, uu.x, uh); vh = fmaf(h0, vv.x, vh);
      uh = fmaf(h1, uu.y, uh); vh = fmaf(h1, vv.y, vh);
      uh = fmaf(h2, uu.z, uh); vh = fmaf(h2, vv.z, vh);
      uh = fmaf(h3, uu.w, uh); vh = fmaf(h3, vv.w, vh);
    }
  }

  float ev = __expf(-vh);
  float eu = __expf(-uh);
  ((float2*)evh)[row*NF + lane] = make_float2(ev, hv);
  eU[row*NF + lane] = eu;

  float pi = wave_sum(hv * attw[lane]);
  float pj = wave_sum(hv * attw[NF + lane]);
  if (lane == 0){ li[row] = pi; lj[row] = pj; }
}

extern "C" __global__ __launch_bounds__(256)
void k_main(const float* __restrict__ attb_p,
            const float* __restrict__ lng,
            const float* __restrict__ lnb,
            const float* __restrict__ ws,
            float* __restrict__ out)
{
  const float* r   = ws;
  const float* evh = ws + NN;
  const float* eU  = evh + NB*NN*NF*2;
  const float* li  = eU + NB*NN*NF;
  const float* lj  = li + NB*NN;

  __shared__ float s_c[4][NN];        // softmax*r per wave's i
  __shared__ float s_evh[JC*NF*2];    // interleaved {eV, h} chunk

  const int tid  = threadIdx.x;
  const int w    = tid >> 6;
  const int lane = tid & 63;          // = feature f
  const int b    = blockIdx.x >> 7;
  const int i    = (blockIdx.x & 127)*4 + w;

  const float attb = attb_p[0];
  const float li_s = li[b*NN + i];

  // --- softmax over j (own i per wave), fold in r[j] ---
  float lv[8];
  float m = -1e30f;
  #pragma unroll
  for (int t = 0; t < 8; t++){
    int j = lane + 64*t;
    float l = li_s + lj[b*NN + j] + attb;
    l = (l > 0.f) ? l : NEG_SLOPE*l;
    lv[t] = l;
    m = fmaxf(m, l);
  }
  m = wave_max(m);
  float S = 0.f;
  #pragma unroll
  for (int t = 0; t < 8; t++){ lv[t] = __expf(lv[t] - m); S += lv[t]; }
  S = wave_sum(S);
  float inv = __builtin_amdgcn_rcpf(S);
  #pragma unroll
  for (int t = 0; t < 8; t++){
    int j = lane + 64*t;
    s_c[w][j] = lv[t]*inv*r[j];
  }

  const float eu = eU[(b*NN + i)*NF + lane];
  float acc = 0.f;
  __syncthreads();

  // --- main contraction over j, staged in LDS chunks ---
  for (int c0 = 0; c0 < NN; c0 += JC){
    const float4* g4 = (const float4*)(evh + (b*NN + c0)*NF*2);
    float4* s4 = (float4*)s_evh;
    #pragma unroll
    for (int t = 0; t < (JC*NF*2/4)/256; t++){
      s4[tid + t*256] = g4[tid + t*256];
    }
    __syncthreads();
    const float2* sevh2 = (const float2*)s_evh;
    #pragma unroll 8
    for (int jj = 0; jj < JC; jj++){
      float cj = s_c[w][c0 + jj];          // LDS broadcast
      float2 eh = sevh2[jj*NF + lane];     // ds_read_b64 {eV, h}
      float q = fmaf(eu, eh.x, 1.0f);      // 1 + eU*eV
      acc = fmaf(cj, eh.y * __builtin_amdgcn_rcpf(q), acc);
    }
    __syncthreads();
  }

  // --- layernorm over f (wave = one row) ---
  float s1 = wave_sum(acc);
  float s2 = wave_sum(acc*acc);
  float mu  = s1 * (1.f/NF);
  float var = s2 * (1.f/NF) - mu*mu;
  float rs  = __builtin_amdgcn_rsqf(var + LN_EPS);
  float o = (acc - mu)*rs*lng[lane] + lnb[lane];
  out[(b*NN + i)*NF + lane] = o;
}

extern "C" void kernel_launch(void* const* d_in, const int* in_sizes, int n_in,
                              void* d_out, int out_size, void* d_ws, size_t ws_size,
                              hipStream_t stream)
{
  const float* x    = (const float*)d_in[0];
  const float* adj  = (const float*)d_in[1];
  const float* Ww   = (const float*)d_in[2];
  const float* Wb   = (const float*)d_in[3];
  const float* Uw   = (const float*)d_in[4];
  const float* Ub   = (const float*)d_in[5];
  const float* Vw   = (const float*)d_in[6];
  const float* Vb   = (const float*)d_in[7];
  const float* attw = (const float*)d_in[8];
  const float* attb = (const float*)d_in[9];
  const float* lng  = (const float*)d_in[10];
  const float* lnb  = (const float*)d_in[11];
  float* ws = (float*)d_ws;
  float* outp = (float*)d_out;

  hipLaunchKernelGGL(k_setup, dim3(NB*NN + NN), dim3(64), 0, stream,
                     x, adj, Ww, Wb, Uw, Ub, Vw, Vb, attw, ws);
  hipLaunchKernelGGL(k_main, dim3(NB*NN/4), dim3(256), 0, stream,
                     attb, lng, lnb, ws, outp);
}

// Round 3
// 103.693 us; speedup vs baseline: 1.0108x; 1.0108x over previous
//
#include <hip/hip_runtime.h>

#define NB 4
#define NN 512
#define NF 64
#define NEG_SLOPE 0.2f
#define LN_EPS 1e-5f

__device__ __forceinline__ float wave_sum(float v){
  #pragma unroll
  for (int d = 32; d; d >>= 1) v += __shfl_xor(v, d, 64);
  return v;
}
__device__ __forceinline__ float wave_max(float v){
  #pragma unroll
  for (int d = 32; d; d >>= 1) v = fmaxf(v, __shfl_xor(v, d, 64));
  return v;
}

// ws layout (floats):
//   r   [NN]              adj row-sums
//   evh [NB*NN*NF*2]      interleaved {exp(-Vh), h} per (b,n,f)
//   eU  [NB*NN*NF]        exp(-Uh)
//   li  [NB*NN]           h . a_i
//   lj  [NB*NN]           h . a_j

extern "C" __global__ __launch_bounds__(64)
void k_setup(const float* __restrict__ x, const float* __restrict__ adj,
             const float* __restrict__ Ww, const float* __restrict__ Wb,
             const float* __restrict__ Uw, const float* __restrict__ Ub,
             const float* __restrict__ Vw, const float* __restrict__ Vb,
             const float* __restrict__ attw,
             float* __restrict__ ws)
{
  float* r   = ws;
  float* evh = ws + NN;
  float* eU  = evh + NB*NN*NF*2;
  float* li  = eU + NB*NN*NF;
  float* lj  = li + NB*NN;

  const int blk  = blockIdx.x;
  const int lane = threadIdx.x;

  if (blk >= NB*NN) {               // adj row-sum blocks
    int j = blk - NB*NN;
    const float2* a2 = (const float2*)(adj + j*NN);
    float s = 0.f;
    #pragma unroll
    for (int t = 0; t < 4; t++){
      float2 a = a2[lane + 64*t];
      s += a.x + a.y;
    }
    s = wave_sum(s);
    if (lane == 0) r[j] = s;
    return;
  }

  const int row = blk;              // b*NN + n
  __shared__ float sx[NF];
  __shared__ float sh[NF];

  sx[lane] = x[row*NF + lane];
  __syncthreads();

  // h = x @ Ww^T + Wb  (lane = output feature)
  float hv = Wb[lane];
  {
    const float4* w4 = (const float4*)(Ww + lane*NF);
    #pragma unroll
    for (int t = 0; t < 16; t++){
      float4 w = w4[t];
      hv = fmaf(sx[4*t+0], w.x, hv);
      hv = fmaf(sx[4*t+1], w.y, hv);
      hv = fmaf(sx[4*t+2], w.z, hv);
      hv = fmaf(sx[4*t+3], w.w, hv);
    }
  }
  sh[lane] = hv;
  __syncthreads();

  float uh = Ub[lane];
  float vh = Vb[lane];
  {
    const float4* u4 = (const float4*)(Uw + lane*NF);
    const float4* v4 = (const float4*)(Vw + lane*NF);
    #pragma unroll
    for (int t = 0; t < 16; t++){
      float4 uu = u4[t]; float4 vv = v4[t];
      float h0 = sh[4*t+0], h1 = sh[4*t+1], h2 = sh[4*t+2], h3 = sh[4*t+3];
      uh = fmaf(h0, uu.x, uh); vh = fmaf(h0, vv.x, vh);
      uh = fmaf(h1, uu.y, uh); vh = fmaf(h1, vv.y, vh);
      uh = fmaf(h2, uu.z, uh); vh = fmaf(h2, vv.z, vh);
      uh = fmaf(h3, uu.w, uh); vh = fmaf(h3, vv.w, vh);
    }
  }

  float ev = __expf(-vh);
  float eu = __expf(-uh);
  ((float2*)evh)[row*NF + lane] = make_float2(ev, hv);
  eU[row*NF + lane] = eu;

  float pi = wave_sum(hv * attw[lane]);
  float pj = wave_sum(hv * attw[NF + lane]);
  if (lane == 0){ li[row] = pi; lj[row] = pj; }
}

// Block = 4 waves = 4 i-rows; wave w computes softmax for i0+w, then all 4 i's
// over j-quarter [w*128, w*128+128) with eh straight from L2 (coalesced
// dwordx2) and c[j][0..3] via one ds_read_b128 broadcast. Partials reduced
// through LDS, then per-wave layernorm.
extern "C" __global__ __launch_bounds__(256)
void k_main(const float* __restrict__ attb_p,
            const float* __restrict__ lng,
            const float* __restrict__ lnb,
            const float* __restrict__ ws,
            float* __restrict__ out)
{
  const float* r   = ws;
  const float* evh = ws + NN;
  const float* eU  = evh + NB*NN*NF*2;
  const float* li  = eU + NB*NN*NF;
  const float* lj  = li + NB*NN;

  __shared__ float s_c[NN][4];          // c[j][i_local] — b128 broadcast reads
  __shared__ float s_part[4][4][NF];    // [wave][i_local][f]

  const int tid  = threadIdx.x;
  const int w    = tid >> 6;
  const int lane = tid & 63;            // = feature f
  const int b    = blockIdx.x >> 7;
  const int i0   = (blockIdx.x & 127) * 4;
  const int i    = i0 + w;              // this wave's softmax row

  const float attb = attb_p[0];
  const float li_s = li[b*NN + i];

  // --- softmax over all j for row i, fold in r[j], store transposed ---
  float lv[8];
  float m = -1e30f;
  #pragma unroll
  for (int t = 0; t < 8; t++){
    int j = lane + 64*t;
    float l = li_s + lj[b*NN + j] + attb;
    l = (l > 0.f) ? l : NEG_SLOPE*l;
    lv[t] = l;
    m = fmaxf(m, l);
  }
  m = wave_max(m);
  float S = 0.f;
  #pragma unroll
  for (int t = 0; t < 8; t++){ lv[t] = __expf(lv[t] - m); S += lv[t]; }
  S = wave_sum(S);
  float inv = __builtin_amdgcn_rcpf(S);
  #pragma unroll
  for (int t = 0; t < 8; t++){
    int j = lane + 64*t;
    s_c[j][w] = lv[t]*inv*r[j];
  }

  // eu for all 4 of the block's rows
  const float eu0 = eU[(b*NN + i0 + 0)*NF + lane];
  const float eu1 = eU[(b*NN + i0 + 1)*NF + lane];
  const float eu2 = eU[(b*NN + i0 + 2)*NF + lane];
  const float eu3 = eU[(b*NN + i0 + 3)*NF + lane];

  __syncthreads();

  // --- main contraction: this wave handles j in [w*128, w*128+128) ---
  const float2* evh2 = (const float2*)evh + (size_t)(b*NN)*NF;
  float a0 = 0.f, a1 = 0.f, a2 = 0.f, a3 = 0.f;
  const int j0 = w*128;
  #pragma unroll 8
  for (int jj = 0; jj < 128; jj++){
    int j = j0 + jj;
    float2 eh = evh2[j*NF + lane];              // coalesced, L2-resident
    float4 c4 = *(const float4*)&s_c[j][0];     // LDS broadcast (same addr all lanes)
    float q0 = fmaf(eu0, eh.x, 1.0f);
    float q1 = fmaf(eu1, eh.x, 1.0f);
    float q2 = fmaf(eu2, eh.x, 1.0f);
    float q3 = fmaf(eu3, eh.x, 1.0f);
    a0 = fmaf(c4.x, eh.y * __builtin_amdgcn_rcpf(q0), a0);
    a1 = fmaf(c4.y, eh.y * __builtin_amdgcn_rcpf(q1), a1);
    a2 = fmaf(c4.z, eh.y * __builtin_amdgcn_rcpf(q2), a2);
    a3 = fmaf(c4.w, eh.y * __builtin_amdgcn_rcpf(q3), a3);
  }

  s_part[w][0][lane] = a0;
  s_part[w][1][lane] = a1;
  s_part[w][2][lane] = a2;
  s_part[w][3][lane] = a3;
  __syncthreads();

  // --- combine partials for row i = i0+w, then layernorm over f ---
  float acc = s_part[0][w][lane] + s_part[1][w][lane]
            + s_part[2][w][lane] + s_part[3][w][lane];

  float s1 = wave_sum(acc);
  float s2 = wave_sum(acc*acc);
  float mu  = s1 * (1.f/NF);
  float var = s2 * (1.f/NF) - mu*mu;
  float rs  = __builtin_amdgcn_rsqf(var + LN_EPS);
  float o = (acc - mu)*rs*lng[lane] + lnb[lane];
  out[(b*NN + i)*NF + lane] = o;
}

extern "C" void kernel_launch(void* const* d_in, const int* in_sizes, int n_in,
                              void* d_out, int out_size, void* d_ws, size_t ws_size,
                              hipStream_t stream)
{
  const float* x    = (const float*)d_in[0];
  const float* adj  = (const float*)d_in[1];
  const float* Ww   = (const float*)d_in[2];
  const float* Wb   = (const float*)d_in[3];
  const float* Uw   = (const float*)d_in[4];
  const float* Ub   = (const float*)d_in[5];
  const float* Vw   = (const float*)d_in[6];
  const float* Vb   = (const float*)d_in[7];
  const float* attw = (const float*)d_in[8];
  const float* attb = (const float*)d_in[9];
  const float* lng  = (const float*)d_in[10];
  const float* lnb  = (const float*)d_in[11];
  float* ws = (float*)d_ws;
  float* outp = (float*)d_out;

  hipLaunchKernelGGL(k_setup, dim3(NB*NN + NN), dim3(64), 0, stream,
                     x, adj, Ww, Wb, Uw, Ub, Vw, Vb, attw, ws);
  hipLaunchKernelGGL(k_main, dim3(NB*NN/4), dim3(256), 0, stream,
                     attb, lng, lnb, ws, outp);
}

// Round 4
// 98.441 us; speedup vs baseline: 1.0647x; 1.0533x over previous
//
#include <hip/hip_runtime.h>

#define NB 4
#define NN 512
#define NF 64
#define NEG_SLOPE 0.2f
#define LN_EPS 1e-5f
#define WP 66   // padded LDS row stride (words): bank = (2*lane + c) % 32 -> 2-way only

__device__ __forceinline__ float wave_sum(float v){
  #pragma unroll
  for (int d = 32; d; d >>= 1) v += __shfl_xor(v, d, 64);
  return v;
}
__device__ __forceinline__ float wave_max(float v){
  #pragma unroll
  for (int d = 32; d; d >>= 1) v = fmaxf(v, __shfl_xor(v, d, 64));
  return v;
}

// ws layout (floats):
//   r   [NN]              adj row-sums
//   evh [NB*NN*NF*2]      interleaved {exp(-Vh), h} per (b,n,f)
//   eU  [NB*NN*NF]        exp(-Uh)
//   li  [NB*NN]           h . a_i
//   lj  [NB*NN]           h . a_j

// 512 blocks x 256 threads. Block g: rows g*4+w (w = wave), adj row-sum j = g.
// Weights staged to LDS coalesced once per block; GEMVs read LDS only.
extern "C" __global__ __launch_bounds__(256, 2)
void k_setup(const float* __restrict__ x, const float* __restrict__ adj,
             const float* __restrict__ Ww, const float* __restrict__ Wb,
             const float* __restrict__ Uw, const float* __restrict__ Ub,
             const float* __restrict__ Vw, const float* __restrict__ Vb,
             const float* __restrict__ attw,
             float* __restrict__ ws)
{
  float* r   = ws;
  float* evh = ws + NN;
  float* eU  = evh + NB*NN*NF*2;
  float* li  = eU + NB*NN*NF;
  float* lj  = li + NB*NN;

  __shared__ float s_w[3*64*WP];   // W, U, V padded [f][c]
  __shared__ float s_x[4][NF];
  __shared__ float s_h[4][NF];
  __shared__ float s_red[4];

  const int tid  = threadIdx.x;
  const int w    = tid >> 6;
  const int lane = tid & 63;       // = output feature f
  const int g    = blockIdx.x;
  const int row  = g*4 + w;        // b*NN + n

  // --- stage weights coalesced: 3 x 4096 floats as float4 ---
  {
    const float4* srcs[3] = { (const float4*)Ww, (const float4*)Uw, (const float4*)Vw };
    #pragma unroll
    for (int m = 0; m < 3; m++){
      const float4* src = srcs[m];
      #pragma unroll
      for (int k = 0; k < 4; k++){
        int idx4 = tid + k*256;          // 1024 float4 per matrix
        float4 v = src[idx4];
        int e = idx4 * 4;
        int f = e >> 6, c = e & 63;
        float* dst = &s_w[m*64*WP + f*WP + c];
        dst[0] = v.x; dst[1] = v.y; dst[2] = v.z; dst[3] = v.w;
      }
    }
  }
  s_x[w][lane] = x[row*NF + lane];
  __syncthreads();

  // --- h = x @ Ww^T + Wb (lane = f) ---
  float hv = Wb[lane];
  {
    const float* wr = &s_w[0*64*WP + lane*WP];
    #pragma unroll
    for (int c = 0; c < NF; c += 2){
      float2 xb = *(const float2*)&s_x[w][c];   // LDS broadcast
      float2 wv = *(const float2*)&wr[c];       // 2-way aliased (free)
      hv = fmaf(xb.x, wv.x, hv);
      hv = fmaf(xb.y, wv.y, hv);
    }
  }
  s_h[w][lane] = hv;
  __syncthreads();

  // --- Uh, Vh GEMVs ---
  float uh = Ub[lane];
  float vh = Vb[lane];
  {
    const float* ur = &s_w[1*64*WP + lane*WP];
    const float* vr = &s_w[2*64*WP + lane*WP];
    #pragma unroll
    for (int c = 0; c < NF; c += 2){
      float2 hb = *(const float2*)&s_h[w][c];
      float2 uv = *(const float2*)&ur[c];
      float2 vv = *(const float2*)&vr[c];
      uh = fmaf(hb.x, uv.x, uh); uh = fmaf(hb.y, uv.y, uh);
      vh = fmaf(hb.x, vv.x, vh); vh = fmaf(hb.y, vv.y, vh);
    }
  }

  float ev = __expf(-vh);
  float eu = __expf(-uh);
  ((float2*)evh)[row*NF + lane] = make_float2(ev, hv);
  eU[row*NF + lane] = eu;

  float pi = wave_sum(hv * attw[lane]);
  float pj = wave_sum(hv * attw[NF + lane]);
  if (lane == 0){ li[row] = pi; lj[row] = pj; }

  // --- adj row-sum for j = g (coalesced float2, block reduce) ---
  {
    const float2* a2 = (const float2*)(adj + g*NN);
    float2 a = a2[tid];
    float s = wave_sum(a.x + a.y);
    if (lane == 0) s_red[w] = s;
    __syncthreads();
    if (tid == 0) r[g] = s_red[0] + s_red[1] + s_red[2] + s_red[3];
  }
}

// Block = 4 waves = 4 i-rows; wave w computes softmax for i0+w, then all 4 i's
// over j-quarter [w*128, w*128+128) with eh straight from L2 (coalesced
// dwordx2) and c[j][0..3] via one ds_read_b128 broadcast. Partials reduced
// through LDS, then per-wave layernorm.
extern "C" __global__ __launch_bounds__(256)
void k_main(const float* __restrict__ attb_p,
            const float* __restrict__ lng,
            const float* __restrict__ lnb,
            const float* __restrict__ ws,
            float* __restrict__ out)
{
  const float* r   = ws;
  const float* evh = ws + NN;
  const float* eU  = evh + NB*NN*NF*2;
  const float* li  = eU + NB*NN*NF;
  const float* lj  = li + NB*NN;

  __shared__ float s_c[NN][4];          // c[j][i_local]
  __shared__ float s_part[4][4][NF];    // [wave][i_local][f]

  const int tid  = threadIdx.x;
  const int w    = tid >> 6;
  const int lane = tid & 63;            // = feature f
  const int b    = blockIdx.x >> 7;
  const int i0   = (blockIdx.x & 127) * 4;
  const int i    = i0 + w;

  const float attb = attb_p[0];
  const float li_s = li[b*NN + i];

  float lv[8];
  float m = -1e30f;
  #pragma unroll
  for (int t = 0; t < 8; t++){
    int j = lane + 64*t;
    float l = li_s + lj[b*NN + j] + attb;
    l = (l > 0.f) ? l : NEG_SLOPE*l;
    lv[t] = l;
    m = fmaxf(m, l);
  }
  m = wave_max(m);
  float S = 0.f;
  #pragma unroll
  for (int t = 0; t < 8; t++){ lv[t] = __expf(lv[t] - m); S += lv[t]; }
  S = wave_sum(S);
  float inv = __builtin_amdgcn_rcpf(S);
  #pragma unroll
  for (int t = 0; t < 8; t++){
    int j = lane + 64*t;
    s_c[j][w] = lv[t]*inv*r[j];
  }

  const float eu0 = eU[(b*NN + i0 + 0)*NF + lane];
  const float eu1 = eU[(b*NN + i0 + 1)*NF + lane];
  const float eu2 = eU[(b*NN + i0 + 2)*NF + lane];
  const float eu3 = eU[(b*NN + i0 + 3)*NF + lane];

  __syncthreads();

  const float2* evh2 = (const float2*)evh + (size_t)(b*NN)*NF;
  float a0 = 0.f, a1 = 0.f, a2 = 0.f, a3 = 0.f;
  const int j0 = w*128;
  #pragma unroll 8
  for (int jj = 0; jj < 128; jj++){
    int j = j0 + jj;
    float2 eh = evh2[j*NF + lane];              // coalesced, L2-resident
    float4 c4 = *(const float4*)&s_c[j][0];     // LDS broadcast
    float q0 = fmaf(eu0, eh.x, 1.0f);
    float q1 = fmaf(eu1, eh.x, 1.0f);
    float q2 = fmaf(eu2, eh.x, 1.0f);
    float q3 = fmaf(eu3, eh.x, 1.0f);
    a0 = fmaf(c4.x, eh.y * __builtin_amdgcn_rcpf(q0), a0);
    a1 = fmaf(c4.y, eh.y * __builtin_amdgcn_rcpf(q1), a1);
    a2 = fmaf(c4.z, eh.y * __builtin_amdgcn_rcpf(q2), a2);
    a3 = fmaf(c4.w, eh.y * __builtin_amdgcn_rcpf(q3), a3);
  }

  s_part[w][0][lane] = a0;
  s_part[w][1][lane] = a1;
  s_part[w][2][lane] = a2;
  s_part[w][3][lane] = a3;
  __syncthreads();

  float acc = s_part[0][w][lane] + s_part[1][w][lane]
            + s_part[2][w][lane] + s_part[3][w][lane];

  float s1 = wave_sum(acc);
  float s2 = wave_sum(acc*acc);
  float mu  = s1 * (1.f/NF);
  float var = s2 * (1.f/NF) - mu*mu;
  float rs  = __builtin_amdgcn_rsqf(var + LN_EPS);
  float o = (acc - mu)*rs*lng[lane] + lnb[lane];
  out[(b*NN + i)*NF + lane] = o;
}

extern "C" void kernel_launch(void* const* d_in, const int* in_sizes, int n_in,
                              void* d_out, int out_size, void* d_ws, size_t ws_size,
                              hipStream_t stream)
{
  const float* x    = (const float*)d_in[0];
  const float* adj  = (const float*)d_in[1];
  const float* Ww   = (const float*)d_in[2];
  const float* Wb   = (const float*)d_in[3];
  const float* Uw   = (const float*)d_in[4];
  const float* Ub   = (const float*)d_in[5];
  const float* Vw   = (const float*)d_in[6];
  const float* Vb   = (const float*)d_in[7];
  const float* attw = (const float*)d_in[8];
  const float* attb = (const float*)d_in[9];
  const float* lng  = (const float*)d_in[10];
  const float* lnb  = (const float*)d_in[11];
  float* ws = (float*)d_ws;
  float* outp = (float*)d_out;

  hipLaunchKernelGGL(k_setup, dim3(NN), dim3(256), 0, stream,
                     x, adj, Ww, Wb, Uw, Ub, Vw, Vb, attw, ws);
  hipLaunchKernelGGL(k_main, dim3(NB*NN/4), dim3(256), 0, stream,
                     attb, lng, lnb, ws, outp);
}

// Round 5
// 93.979 us; speedup vs baseline: 1.1152x; 1.0475x over previous
//
#include <hip/hip_runtime.h>

#define NB 4
#define NN 512
#define NF 64
#define NEG_SLOPE 0.2f
#define LN_EPS 1e-5f
#define WP 66   // padded LDS row stride (words): bank = (2*lane + c) % 32 -> 2-way only

__device__ __forceinline__ float wave_sum(float v){
  #pragma unroll
  for (int d = 32; d; d >>= 1) v += __shfl_xor(v, d, 64);
  return v;
}
__device__ __forceinline__ float wave_max(float v){
  #pragma unroll
  for (int d = 32; d; d >>= 1) v = fmaxf(v, __shfl_xor(v, d, 64));
  return v;
}
__device__ __forceinline__ unsigned int rnd_bf_hi(float f){
  union { float f; unsigned int i; } v; v.f = f;
  return (v.i + 0x7fffu + ((v.i >> 16) & 1u)) & 0xffff0000u;
}

// ws layout (floats / words):
//   r   [NN]              adj row-sums (f32)
//   evh [NB*NN*NF]        packed uint32: hi16 = bf16(h), lo16 = bf16(exp(-Vh))
//   eU  [NB*NN*NF]        exp(-Uh) (f32)
//   li  [NB*NN]           h . a_i
//   lj  [NB*NN]           h . a_j

// 512 blocks x 256 threads. Block g: rows g*4+w (w = wave), adj row-sum j = g.
// Weights staged to LDS coalesced once per block; GEMVs read LDS only.
extern "C" __global__ __launch_bounds__(256, 2)
void k_setup(const float* __restrict__ x, const float* __restrict__ adj,
             const float* __restrict__ Ww, const float* __restrict__ Wb,
             const float* __restrict__ Uw, const float* __restrict__ Ub,
             const float* __restrict__ Vw, const float* __restrict__ Vb,
             const float* __restrict__ attw,
             float* __restrict__ ws)
{
  float* r            = ws;
  unsigned int* evh   = (unsigned int*)(ws + NN);
  float* eU           = ws + NN + NB*NN*NF;
  float* li           = eU + NB*NN*NF;
  float* lj           = li + NB*NN;

  __shared__ float s_w[3*64*WP];   // W, U, V padded [f][c]
  __shared__ float s_x[4][NF];
  __shared__ float s_h[4][NF];
  __shared__ float s_red[4];

  const int tid  = threadIdx.x;
  const int w    = tid >> 6;
  const int lane = tid & 63;       // = output feature f
  const int g    = blockIdx.x;
  const int row  = g*4 + w;        // b*NN + n

  // --- stage weights coalesced: 3 x 4096 floats as float4 ---
  {
    const float4* srcs[3] = { (const float4*)Ww, (const float4*)Uw, (const float4*)Vw };
    #pragma unroll
    for (int m = 0; m < 3; m++){
      const float4* src = srcs[m];
      #pragma unroll
      for (int k = 0; k < 4; k++){
        int idx4 = tid + k*256;          // 1024 float4 per matrix
        float4 v = src[idx4];
        int e = idx4 * 4;
        int f = e >> 6, c = e & 63;
        float* dst = &s_w[m*64*WP + f*WP + c];
        dst[0] = v.x; dst[1] = v.y; dst[2] = v.z; dst[3] = v.w;
      }
    }
  }
  s_x[w][lane] = x[row*NF + lane];
  __syncthreads();

  // --- h = x @ Ww^T + Wb (lane = f) ---
  float hv = Wb[lane];
  {
    const float* wr = &s_w[0*64*WP + lane*WP];
    #pragma unroll
    for (int c = 0; c < NF; c += 2){
      float2 xb = *(const float2*)&s_x[w][c];   // LDS broadcast
      float2 wv = *(const float2*)&wr[c];       // 2-way aliased (free)
      hv = fmaf(xb.x, wv.x, hv);
      hv = fmaf(xb.y, wv.y, hv);
    }
  }
  s_h[w][lane] = hv;
  __syncthreads();

  // --- Uh, Vh GEMVs ---
  float uh = Ub[lane];
  float vh = Vb[lane];
  {
    const float* ur = &s_w[1*64*WP + lane*WP];
    const float* vr = &s_w[2*64*WP + lane*WP];
    #pragma unroll
    for (int c = 0; c < NF; c += 2){
      float2 hb = *(const float2*)&s_h[w][c];
      float2 uv = *(const float2*)&ur[c];
      float2 vv = *(const float2*)&vr[c];
      uh = fmaf(hb.x, uv.x, uh); uh = fmaf(hb.y, uv.y, uh);
      vh = fmaf(hb.x, vv.x, vh); vh = fmaf(hb.y, vv.y, vh);
    }
  }

  float ev = __expf(-vh);
  float eu = __expf(-uh);
  evh[row*NF + lane] = rnd_bf_hi(hv) | (rnd_bf_hi(ev) >> 16);
  eU[row*NF + lane] = eu;

  float pi = wave_sum(hv * attw[lane]);
  float pj = wave_sum(hv * attw[NF + lane]);
  if (lane == 0){ li[row] = pi; lj[row] = pj; }

  // --- adj row-sum for j = g (coalesced float2, block reduce) ---
  {
    const float2* a2 = (const float2*)(adj + g*NN);
    float2 a = a2[tid];
    float s = wave_sum(a.x + a.y);
    if (lane == 0) s_red[w] = s;
    __syncthreads();
    if (tid == 0) r[g] = s_red[0] + s_red[1] + s_red[2] + s_red[3];
  }
}

// Block = 4 waves = 4 i-rows; wave w computes softmax for i0+w, then all 4 i's
// over j-quarter [w*128, w*128+128). Packed {bf16(h), bf16(eV)} loaded as one
// coalesced dword from L2; c[j][0..3] via one ds_read_b128 broadcast.
// Partials reduced through LDS, then per-wave layernorm.
extern "C" __global__ __launch_bounds__(256)
void k_main(const float* __restrict__ attb_p,
            const float* __restrict__ lng,
            const float* __restrict__ lnb,
            const float* __restrict__ ws,
            float* __restrict__ out)
{
  const float* r          = ws;
  const unsigned int* evh = (const unsigned int*)(ws + NN);
  const float* eU         = ws + NN + NB*NN*NF;
  const float* li         = eU + NB*NN*NF;
  const float* lj         = li + NB*NN;

  __shared__ float s_c[NN][4];          // c[j][i_local]
  __shared__ float s_part[4][4][NF];    // [wave][i_local][f]

  const int tid  = threadIdx.x;
  const int w    = tid >> 6;
  const int lane = tid & 63;            // = feature f
  const int b    = blockIdx.x >> 7;
  const int i0   = (blockIdx.x & 127) * 4;
  const int i    = i0 + w;

  const float attb = attb_p[0];
  const float li_s = li[b*NN + i];

  float lv[8];
  float m = -1e30f;
  #pragma unroll
  for (int t = 0; t < 8; t++){
    int j = lane + 64*t;
    float l = li_s + lj[b*NN + j] + attb;
    l = (l > 0.f) ? l : NEG_SLOPE*l;
    lv[t] = l;
    m = fmaxf(m, l);
  }
  m = wave_max(m);
  float S = 0.f;
  #pragma unroll
  for (int t = 0; t < 8; t++){ lv[t] = __expf(lv[t] - m); S += lv[t]; }
  S = wave_sum(S);
  float inv = __builtin_amdgcn_rcpf(S);
  #pragma unroll
  for (int t = 0; t < 8; t++){
    int j = lane + 64*t;
    s_c[j][w] = lv[t]*inv*r[j];
  }

  const float eu0 = eU[(b*NN + i0 + 0)*NF + lane];
  const float eu1 = eU[(b*NN + i0 + 1)*NF + lane];
  const float eu2 = eU[(b*NN + i0 + 2)*NF + lane];
  const float eu3 = eU[(b*NN + i0 + 3)*NF + lane];

  __syncthreads();

  const unsigned int* evhb = evh + (size_t)(b*NN)*NF;
  float a0 = 0.f, a1 = 0.f, a2 = 0.f, a3 = 0.f;
  const int j0 = w*128;
  #pragma unroll 8
  for (int jj = 0; jj < 128; jj++){
    int j = j0 + jj;
    unsigned int u = evhb[j*NF + lane];         // coalesced dword, L2-resident
    union { unsigned int i; float f; } hh, ee;
    hh.i = u & 0xffff0000u;                     // bf16(h)
    ee.i = u << 16;                             // bf16(eV)
    float4 c4 = *(const float4*)&s_c[j][0];     // LDS broadcast
    float q0 = fmaf(eu0, ee.f, 1.0f);
    float q1 = fmaf(eu1, ee.f, 1.0f);
    float q2 = fmaf(eu2, ee.f, 1.0f);
    float q3 = fmaf(eu3, ee.f, 1.0f);
    a0 = fmaf(c4.x, hh.f * __builtin_amdgcn_rcpf(q0), a0);
    a1 = fmaf(c4.y, hh.f * __builtin_amdgcn_rcpf(q1), a1);
    a2 = fmaf(c4.z, hh.f * __builtin_amdgcn_rcpf(q2), a2);
    a3 = fmaf(c4.w, hh.f * __builtin_amdgcn_rcpf(q3), a3);
  }

  s_part[w][0][lane] = a0;
  s_part[w][1][lane] = a1;
  s_part[w][2][lane] = a2;
  s_part[w][3][lane] = a3;
  __syncthreads();

  float acc = s_part[0][w][lane] + s_part[1][w][lane]
            + s_part[2][w][lane] + s_part[3][w][lane];

  float s1 = wave_sum(acc);
  float s2 = wave_sum(acc*acc);
  float mu  = s1 * (1.f/NF);
  float var = s2 * (1.f/NF) - mu*mu;
  float rs  = __builtin_amdgcn_rsqf(var + LN_EPS);
  float o = (acc - mu)*rs*lng[lane] + lnb[lane];
  out[(b*NN + i)*NF + lane] = o;
}

extern "C" void kernel_launch(void* const* d_in, const int* in_sizes, int n_in,
                              void* d_out, int out_size, void* d_ws, size_t ws_size,
                              hipStream_t stream)
{
  const float* x    = (const float*)d_in[0];
  const float* adj  = (const float*)d_in[1];
  const float* Ww   = (const float*)d_in[2];
  const float* Wb   = (const float*)d_in[3];
  const float* Uw   = (const float*)d_in[4];
  const float* Ub   = (const float*)d_in[5];
  const float* Vw   = (const float*)d_in[6];
  const float* Vb   = (const float*)d_in[7];
  const float* attw = (const float*)d_in[8];
  const float* attb = (const float*)d_in[9];
  const float* lng  = (const float*)d_in[10];
  const float* lnb  = (const float*)d_in[11];
  float* ws = (float*)d_ws;
  float* outp = (float*)d_out;

  hipLaunchKernelGGL(k_setup, dim3(NN), dim3(256), 0, stream,
                     x, adj, Ww, Wb, Uw, Ub, Vw, Vb, attw, ws);
  hipLaunchKernelGGL(k_main, dim3(NB*NN/4), dim3(256), 0, stream,
                     attb, lng, lnb, ws, outp);
}